// Round 11
// baseline (66.685 us; speedup 1.0000x reference)
//
#include <hip/hip_runtime.h>
#include <stdint.h>

// ---------------------------------------------------------------------------
// FractalLinear: IFS chaos game (JAX threefry-exact) + bilinear gather/scatter
// Round 11: gather/scatter split to make ALL x-traffic sequential.
//   K1 chaos  -> rec[1000]
//   K2 build  -> 16 column-chunk buckets: rowptr[17], rec2={xl,xw} sorted,
//                rec3={yl,yw} sorted
//   K3 A (16x2048 blocks): per (chunk,row): skip if chunk empty; else stage
//        4KB of x coalesced -> LDS, emit XV[row][i] (dense 8MB intermediate)
//   K4 B (2048 blocks): XV coalesced read + LDS atomic scatter + full-line
//        nontemporal epilogue (R4-proven)
// Requires ws >= ~8.5MB for XV; falls back to the round-4 path otherwise.
// Theory: random 64B gathers run ~1.5TB/s; sequential ~6.3TB/s. Trade 51MB
// random for (occupied-chunks * 4KB * 2048) sequential + 16MB XV traffic.
// ---------------------------------------------------------------------------
#ifndef PRNG_PARTITIONABLE
#define PRNG_PARTITIONABLE 1
#endif

namespace {

constexpr int kH  = 8192;
constexpr int kW  = 16384;
constexpr int kNT = 8;
constexpr int kNP = 1000;
constexpr int kCI = 10;
constexpr int kCh = 16;               // column chunks
constexpr int kChW = kW / kCh;        // 1024 columns per chunk
constexpr int kRPB = 2;               // fallback: rows per block

// ws layout (byte offsets)
constexpr size_t kOffRec    = 0;          // 1000 * int4  = 16000
constexpr size_t kOffRowPtr = 16384;      // 17 * u32
constexpr size_t kOffRec2   = 16512;      // 1000 * uint2 = 8000
constexpr size_t kOffRec3   = 24576;      // 1000 * uint2 = 8000
constexpr size_t kOffXV     = 32768;      // 2048 * 1024 * 4 = 8388608
constexpr size_t kWsNeeded  = kOffXV + (size_t)2048 * 1024 * 4;

typedef float floatx4 __attribute__((ext_vector_type(4)));  // nontemporal-OK

__device__ __forceinline__ uint32_t rotl32(uint32_t x, int n) {
  return (x << n) | (x >> (32 - n));
}

// Threefry-2x32, 20 rounds (Random123 / JAX convention).
__device__ void threefry2x32(uint32_t k0, uint32_t k1, uint32_t c0, uint32_t c1,
                             uint32_t& o0, uint32_t& o1) {
  const uint32_t ks2 = k0 ^ k1 ^ 0x1BD11BDAu;
  uint32_t x0 = c0 + k0, x1 = c1 + k1;
#define TF_R(r) { x0 += x1; x1 = rotl32(x1, (r)); x1 ^= x0; }
  TF_R(13) TF_R(15) TF_R(26) TF_R(6)
  x0 += k1;  x1 += ks2 + 1u;
  TF_R(17) TF_R(29) TF_R(16) TF_R(24)
  x0 += ks2; x1 += k0 + 2u;
  TF_R(13) TF_R(15) TF_R(26) TF_R(6)
  x0 += k0;  x1 += k1 + 3u;
  TF_R(17) TF_R(29) TF_R(16) TF_R(24)
  x0 += k1;  x1 += ks2 + 4u;
  TF_R(13) TF_R(15) TF_R(26) TF_R(6)
  x0 += ks2; x1 += k0 + 5u;
#undef TF_R
  o0 = x0; o1 = x1;
}

__device__ __forceinline__ uint32_t random_bits32(uint32_t k0, uint32_t k1,
                                                  uint32_t i, uint32_t size) {
#if PRNG_PARTITIONABLE
  uint32_t o0, o1;
  threefry2x32(k0, k1, 0u /* hi(i) */, i, o0, o1);
  (void)size;
  return o0 ^ o1;
#else
  const uint32_t half = size / 2u;
  const uint32_t j = (i < half) ? i : (i - half);
  uint32_t o0, o1;
  threefry2x32(k0, k1, j, j + half, o0, o1);
  return (i < half) ? o0 : o1;
#endif
}

__device__ __forceinline__ float u01(uint32_t bits) {
  return __uint_as_float((bits >> 9) | 0x3f800000u) - 1.0f;
}

// x86 cvttss2si semantics: out-of-range / NaN -> INT_MIN (matches CPU-ref).
__device__ __forceinline__ int cvt_f32_i32_x86(float v) {
  if (!(v >= -2147483648.0f && v < 2147483648.0f)) return (int)0x80000000;
  return (int)v;
}

// ---------------------------------------------------------------------------
// Kernel 1: chaos game, 8 lanes per point (one transform each).
// ---------------------------------------------------------------------------
__global__ __launch_bounds__(256) void fractal_chaos(
    const float* __restrict__ dna, int4* __restrict__ rec) {
  const int gid  = blockIdx.x * blockDim.x + threadIdx.x;
  const int n    = gid >> 3;
  const int lane = gid & 7;
  if (n >= kNP) return;

  uint32_t kp0, kp1, kg0, kg1;
#if PRNG_PARTITIONABLE
  threefry2x32(0u, 1u, 0u, 0u, kp0, kp1);
  threefry2x32(0u, 1u, 0u, 1u, kg0, kg1);
#else
  uint32_t a0, a1, b0, b1;
  threefry2x32(0u, 1u, 0u, 2u, a0, a1);
  threefry2x32(0u, 1u, 1u, 3u, b0, b1);
  kp0 = a0; kp1 = b0; kg0 = a1; kg1 = b1;
#endif

  const float A  = dna[lane * 7 + 0], Bb = dna[lane * 7 + 1];
  const float C  = dna[lane * 7 + 2], D  = dna[lane * 7 + 3];
  const float E  = dna[lane * 7 + 4], F  = dna[lane * 7 + 5];
  const float P  = dna[lane * 7 + 6];

  float z[kCI];
  #pragma unroll
  for (int i = 0; i < kCI; ++i) {
    uint32_t ki0, ki1;
    threefry2x32(kg0, kg1, 0u, (uint32_t)i, ki0, ki1);   // fold_in(kg, i)
    const uint32_t bb = random_bits32(ki0, ki1, (uint32_t)(n * kNT + lane),
                                      (uint32_t)(kNP * kNT));
    const float u = fmaxf(u01(bb), 1.17549435e-38f);
    const float g = -logf(-logf(u));
    z[i] = P + g;
  }

  const uint32_t bx = random_bits32(kp0, kp1, (uint32_t)(2 * n),     2u * kNP);
  const uint32_t by = random_bits32(kp0, kp1, (uint32_t)(2 * n + 1), 2u * kNP);
  float px = u01(bx) * 2.0f - 1.0f;
  float py = u01(by) * 2.0f - 1.0f;

  #pragma unroll
  for (int i = 0; i < kCI; ++i) {
    // argmax over the 8 lanes, first-index tiebreak (matches jnp.argmax)
    float zb = z[i];
    int   bt = lane;
    #pragma unroll
    for (int m = 1; m < 8; m <<= 1) {
      const float zo = __shfl_xor(zb, m, 8);
      const int   to = __shfl_xor(bt, m, 8);
      if (zo > zb || (zo == zb && to < bt)) { zb = zo; bt = to; }
    }
    const float A_ = __shfl(A,  bt, 8), B_ = __shfl(Bb, bt, 8);
    const float C_ = __shfl(C,  bt, 8), D_ = __shfl(D,  bt, 8);
    const float E_ = __shfl(E,  bt, 8), F_ = __shfl(F,  bt, 8);
    const float nx = A_ * px + B_ * py + E_;
    const float ny = C_ * px + D_ * py + F_;
    px = nx; py = ny;
  }

  if (lane == 0) {
    const float xc = ((px + 1.0f) * 0.5f) * (float)(kW - 1);
    const float yc = ((py + 1.0f) * 0.5f) * (float)(kH - 1);
    int xl = cvt_f32_i32_x86(floorf(xc));
    int yl = cvt_f32_i32_x86(floorf(yc));
    xl = min(max(xl, 0), kW - 2);
    yl = min(max(yl, 0), kH - 2);
    const float xw = xc - (float)xl;   // NOT clipped (matches reference)
    const float yw = yc - (float)yl;
    rec[n] = make_int4(xl, __float_as_int(xw), yl, __float_as_int(yw));
  }
}

// ---------------------------------------------------------------------------
// Kernel 2 (1 block, 1024 thr): bucket points by column-chunk (xl >> 10).
// rowptr[17] + rec2 (sorted {xl, xw}) + rec3 (sorted {yl, yw}).
// ---------------------------------------------------------------------------
__global__ __launch_bounds__(1024) void fractal_build(
    const int4* __restrict__ rec, uint32_t* __restrict__ rowptr,
    uint2* __restrict__ rec2, uint2* __restrict__ rec3) {
  __shared__ uint32_t cnt[kCh];
  __shared__ uint32_t cur[kCh];

  const int t = threadIdx.x;
  if (t < kCh) cnt[t] = 0;
  __syncthreads();

  int4 r = make_int4(0, 0, 0, 0);
  int ch = 0;
  const bool hav = t < kNP;
  if (hav) {
    r = rec[t];
    ch = r.x >> 10;
    atomicAdd(&cnt[ch], 1u);
  }
  __syncthreads();

  if (t == 0) {
    uint32_t run = 0;
    #pragma unroll
    for (int k = 0; k < kCh; ++k) {
      rowptr[k] = run;
      cur[k] = run;
      run += cnt[k];
    }
    rowptr[kCh] = run;                 // == kNP
  }
  __syncthreads();

  if (hav) {
    const uint32_t p = atomicAdd(&cur[ch], 1u);
    rec2[p] = make_uint2((uint32_t)r.x, (uint32_t)r.y);
    rec3[p] = make_uint2((uint32_t)r.z, (uint32_t)r.w);
  }
}

// ---------------------------------------------------------------------------
// Kernel A: grid (kCh, B). Per (chunk, row): skip if no points in chunk;
// else stage 4KB of the row coalesced into LDS and emit the bilinear
// x-values XV[row][i] for the chunk's points (sorted index i).
// ---------------------------------------------------------------------------
__global__ __launch_bounds__(256) void fractal_gather(
    const float* __restrict__ x, const uint32_t* __restrict__ rowptr,
    const uint2* __restrict__ rec2, float* __restrict__ XV) {
  const int ch = blockIdx.x;
  const uint32_t s = rowptr[ch], e = rowptr[ch + 1];
  if (s == e) return;                              // chunk has no points

  __shared__ __align__(16) float xb[kChW];         // 4KB
  const int r   = blockIdx.y;
  const int tid = threadIdx.x;
  const int c0  = ch * kChW;
  const float* __restrict__ xrow = x + (size_t)r * kW;

  // coalesced stage: 256 threads x 1 float4 = 1024 floats
  reinterpret_cast<float4*>(xb)[tid] =
      reinterpret_cast<const float4*>(xrow + c0)[tid];
  __syncthreads();

  float* __restrict__ xvrow = XV + (size_t)r * 1024;
  for (uint32_t i = s + tid; i < e; i += 256) {
    const uint2 p = rec2[i];
    const int   xl = (int)p.x;
    const float xw = __uint_as_float(p.y);
    const int loc = xl - c0;
    const float v0 = xb[loc];
    const float v1 = (loc < kChW - 1) ? xb[loc + 1] : xrow[xl + 1];
    xvrow[i] = v0 * (1.0f - xw) + v1 * xw;
  }
}

// ---------------------------------------------------------------------------
// Kernel B: one row per block, 256 threads, 32KB LDS (5 blocks/CU).
// Coalesced XV read + LDS atomic scatter + full-line nontemporal epilogue.
// ---------------------------------------------------------------------------
__global__ __launch_bounds__(256) void fractal_scatter(
    const float* __restrict__ XV, const uint2* __restrict__ rec3,
    const float* __restrict__ bias, float* __restrict__ out) {
  __shared__ __align__(16) float acc[kH];          // 32KB
  const int r   = blockIdx.x;
  const int tid = threadIdx.x;

  // issue point loads first (hidden under the LDS zero)
  float xv[4];
  uint2 p[4];
  #pragma unroll
  for (int j = 0; j < 4; ++j) {
    const int i = tid + j * 256;
    if (i < kNP) {
      xv[j] = XV[(size_t)r * 1024 + i];
      p[j]  = rec3[i];
    }
  }

  float4* acc4 = reinterpret_cast<float4*>(acc);
  #pragma unroll
  for (int j = 0; j < 8; ++j)
    acc4[tid + j * 256] = make_float4(0.f, 0.f, 0.f, 0.f);
  __syncthreads();

  #pragma unroll
  for (int j = 0; j < 4; ++j) {
    const int i = tid + j * 256;
    if (i < kNP) {
      const int   yl = (int)p[j].x;
      const float yw = __uint_as_float(p[j].y);
      atomicAdd(&acc[yl],     xv[j] * (1.0f - yw));
      atomicAdd(&acc[yl + 1], xv[j] * yw);
    }
  }
  __syncthreads();

  const floatx4* __restrict__ bias4 = reinterpret_cast<const floatx4*>(bias);
  floatx4* __restrict__ out4 = reinterpret_cast<floatx4*>(out + (size_t)r * kH);
  #pragma unroll
  for (int j = 0; j < 8; ++j) {
    const int g = tid + j * 256;
    const float4 a  = acc4[g];
    const floatx4 bi = bias4[g];
    floatx4 o;
    o.x = a.x / 1000.0f + bi.x;
    o.y = a.y / 1000.0f + bi.y;
    o.z = a.z / 1000.0f + bi.z;
    o.w = a.w / 1000.0f + bi.w;
    __builtin_nontemporal_store(o, &out4[g]);
  }
}

// ---------------------------------------------------------------------------
// Fallback (ws too small): round-4 apply, 2 rows/block, 1024 threads.
// ---------------------------------------------------------------------------
__global__ __launch_bounds__(1024) void fractal_apply_fb(
    const float* __restrict__ x, const float* __restrict__ bias,
    const int4* __restrict__ rec, float* __restrict__ out, int B) {
  __shared__ __align__(16) float acc[kRPB * kH];
  const int b0 = blockIdx.x * kRPB;
  const int nrows = min(kRPB, B - b0);
  const int tid = threadIdx.x;

  float4* acc4 = reinterpret_cast<float4*>(acc);
  constexpr int N4 = kRPB * kH / 4;
  for (int i = tid; i < N4; i += 1024)
    acc4[i] = make_float4(0.f, 0.f, 0.f, 0.f);
  __syncthreads();

  if (tid < kNP) {
    const int4 r = rec[tid];
    const int   xl = r.x;
    const float xw = __int_as_float(r.y);
    const int   yl = r.z;
    const float yw = __int_as_float(r.w);
    const float xw0 = 1.0f - xw;
    const float w0  = 1.0f - yw;
    const float* xp = x + (size_t)b0 * kW + xl;
    #pragma unroll
    for (int rI = 0; rI < kRPB; ++rI) {
      if (rI < nrows) {
        const float xvv = xp[(size_t)rI * kW] * xw0 + xp[(size_t)rI * kW + 1] * xw;
        atomicAdd(&acc[rI * kH + yl],     xvv * w0);
        atomicAdd(&acc[rI * kH + yl + 1], xvv * yw);
      }
    }
  }
  __syncthreads();

  const floatx4* __restrict__ bias4 = reinterpret_cast<const floatx4*>(bias);
  for (int i = tid; i < N4; i += 1024) {
    const int row = i >> 11;
    const int col = i & 2047;
    if (row < nrows) {
      const float4 a  = acc4[i];
      const floatx4 bi = bias4[col];
      floatx4 o;
      o.x = a.x / 1000.0f + bi.x;
      o.y = a.y / 1000.0f + bi.y;
      o.z = a.z / 1000.0f + bi.z;
      o.w = a.w / 1000.0f + bi.w;
      floatx4* dst = reinterpret_cast<floatx4*>(out + (size_t)(b0 + row) * kH);
      __builtin_nontemporal_store(o, &dst[col]);
    }
  }
}

}  // namespace

extern "C" void kernel_launch(void* const* d_in, const int* in_sizes, int n_in,
                              void* d_out, int out_size, void* d_ws, size_t ws_size,
                              hipStream_t stream) {
  const float* x    = (const float*)d_in[0];   // (2048, 16384)
  const float* dna  = (const float*)d_in[1];   // (56,)
  const float* bias = (const float*)d_in[2];   // (8192,)
  float* out = (float*)d_out;                  // (2048, 8192)

  char* ws = (char*)d_ws;
  int4*     rec    = (int4*)(ws + kOffRec);
  uint32_t* rowptr = (uint32_t*)(ws + kOffRowPtr);
  uint2*    rec2   = (uint2*)(ws + kOffRec2);
  uint2*    rec3   = (uint2*)(ws + kOffRec3);
  float*    XV     = (float*)(ws + kOffXV);

  const int B = in_sizes[0] / kW;              // 2048

  fractal_chaos<<<(kNP * 8 + 255) / 256, 256, 0, stream>>>(dna, rec);

  if (ws_size >= kWsNeeded && B == 2048) {
    fractal_build<<<1, 1024, 0, stream>>>(rec, rowptr, rec2, rec3);
    fractal_gather<<<dim3(kCh, B), 256, 0, stream>>>(x, rowptr, rec2, XV);
    fractal_scatter<<<B, 256, 0, stream>>>(XV, rec3, bias, out);
  } else {
    fractal_apply_fb<<<(B + kRPB - 1) / kRPB, 1024, 0, stream>>>(x, bias, rec,
                                                                 out, B);
  }
}

// Round 12
// 42.282 us; speedup vs baseline: 1.5772x; 1.5772x over previous
//
#include <hip/hip_runtime.h>
#include <stdint.h>

// ---------------------------------------------------------------------------
// FractalLinear: IFS chaos game (JAX threefry-exact) + bilinear gather/scatter
// Round 12: persistent software-pipelined apply.
//   - 512 blocks x 1024 thr, 32KB LDS acc -> 2 blocks/CU, ALL resident.
//   - 4 rows per block, pipelined: scatter(row i) || loads(row i+1) in
//     flight across RAW s_barrier (lgkmcnt-only wait, NO vmcnt drain --
//     __syncthreads would drain the pipeline; this is the HK counted-wait
//     trick at block scope).
//   - epilogue fuses acc-read + bias + nontemporal store + acc-zero.
// Evidence trail: R7/R9/R11 restructures regressed (inversion/compaction/
// split all added serialization); R8 hot-atomics neutral; R10 sort neutral.
// All memory-pattern theories dead => attack phase serialization.
// ---------------------------------------------------------------------------
#ifndef PRNG_PARTITIONABLE
#define PRNG_PARTITIONABLE 1
#endif

namespace {

constexpr int kH  = 8192;
constexpr int kW  = 16384;
constexpr int kNT = 8;
constexpr int kNP = 1000;
constexpr int kCI = 10;
constexpr int kRPB = 4;          // rows per apply block (pipeline depth)

typedef float floatx4 __attribute__((ext_vector_type(4)));  // nontemporal-OK

// Raw barrier: wait only on LDS ops, leave global loads/stores in flight.
// (__syncthreads emits s_waitcnt vmcnt(0) lgkmcnt(0) before s_barrier,
// which would drain the prefetched gather loads every iteration.)
#define BAR_LDS() asm volatile("s_waitcnt lgkmcnt(0)\n\ts_barrier" ::: "memory")

__device__ __forceinline__ uint32_t rotl32(uint32_t x, int n) {
  return (x << n) | (x >> (32 - n));
}

// Threefry-2x32, 20 rounds (Random123 / JAX convention).
__device__ void threefry2x32(uint32_t k0, uint32_t k1, uint32_t c0, uint32_t c1,
                             uint32_t& o0, uint32_t& o1) {
  const uint32_t ks2 = k0 ^ k1 ^ 0x1BD11BDAu;
  uint32_t x0 = c0 + k0, x1 = c1 + k1;
#define TF_R(r) { x0 += x1; x1 = rotl32(x1, (r)); x1 ^= x0; }
  TF_R(13) TF_R(15) TF_R(26) TF_R(6)
  x0 += k1;  x1 += ks2 + 1u;
  TF_R(17) TF_R(29) TF_R(16) TF_R(24)
  x0 += ks2; x1 += k0 + 2u;
  TF_R(13) TF_R(15) TF_R(26) TF_R(6)
  x0 += k0;  x1 += k1 + 3u;
  TF_R(17) TF_R(29) TF_R(16) TF_R(24)
  x0 += k1;  x1 += ks2 + 4u;
  TF_R(13) TF_R(15) TF_R(26) TF_R(6)
  x0 += ks2; x1 += k0 + 5u;
#undef TF_R
  o0 = x0; o1 = x1;
}

__device__ __forceinline__ uint32_t random_bits32(uint32_t k0, uint32_t k1,
                                                  uint32_t i, uint32_t size) {
#if PRNG_PARTITIONABLE
  uint32_t o0, o1;
  threefry2x32(k0, k1, 0u /* hi(i) */, i, o0, o1);
  (void)size;
  return o0 ^ o1;
#else
  const uint32_t half = size / 2u;
  const uint32_t j = (i < half) ? i : (i - half);
  uint32_t o0, o1;
  threefry2x32(k0, k1, j, j + half, o0, o1);
  return (i < half) ? o0 : o1;
#endif
}

__device__ __forceinline__ float u01(uint32_t bits) {
  return __uint_as_float((bits >> 9) | 0x3f800000u) - 1.0f;
}

// x86 cvttss2si semantics: out-of-range / NaN -> INT_MIN (matches CPU-ref).
__device__ __forceinline__ int cvt_f32_i32_x86(float v) {
  if (!(v >= -2147483648.0f && v < 2147483648.0f)) return (int)0x80000000;
  return (int)v;
}

// ---------------------------------------------------------------------------
// Kernel 1: chaos game, 8 lanes per point (one transform each).
// ---------------------------------------------------------------------------
__global__ __launch_bounds__(256) void fractal_chaos(
    const float* __restrict__ dna, int4* __restrict__ rec) {
  const int gid  = blockIdx.x * blockDim.x + threadIdx.x;
  const int n    = gid >> 3;
  const int lane = gid & 7;
  if (n >= kNP) return;

  uint32_t kp0, kp1, kg0, kg1;
#if PRNG_PARTITIONABLE
  threefry2x32(0u, 1u, 0u, 0u, kp0, kp1);
  threefry2x32(0u, 1u, 0u, 1u, kg0, kg1);
#else
  uint32_t a0, a1, b0, b1;
  threefry2x32(0u, 1u, 0u, 2u, a0, a1);
  threefry2x32(0u, 1u, 1u, 3u, b0, b1);
  kp0 = a0; kp1 = b0; kg0 = a1; kg1 = b1;
#endif

  const float A  = dna[lane * 7 + 0], Bb = dna[lane * 7 + 1];
  const float C  = dna[lane * 7 + 2], D  = dna[lane * 7 + 3];
  const float E  = dna[lane * 7 + 4], F  = dna[lane * 7 + 5];
  const float P  = dna[lane * 7 + 6];

  float z[kCI];
  #pragma unroll
  for (int i = 0; i < kCI; ++i) {
    uint32_t ki0, ki1;
    threefry2x32(kg0, kg1, 0u, (uint32_t)i, ki0, ki1);   // fold_in(kg, i)
    const uint32_t bb = random_bits32(ki0, ki1, (uint32_t)(n * kNT + lane),
                                      (uint32_t)(kNP * kNT));
    const float u = fmaxf(u01(bb), 1.17549435e-38f);
    const float g = -logf(-logf(u));
    z[i] = P + g;
  }

  const uint32_t bx = random_bits32(kp0, kp1, (uint32_t)(2 * n),     2u * kNP);
  const uint32_t by = random_bits32(kp0, kp1, (uint32_t)(2 * n + 1), 2u * kNP);
  float px = u01(bx) * 2.0f - 1.0f;
  float py = u01(by) * 2.0f - 1.0f;

  #pragma unroll
  for (int i = 0; i < kCI; ++i) {
    // argmax over the 8 lanes, first-index tiebreak (matches jnp.argmax)
    float zb = z[i];
    int   bt = lane;
    #pragma unroll
    for (int m = 1; m < 8; m <<= 1) {
      const float zo = __shfl_xor(zb, m, 8);
      const int   to = __shfl_xor(bt, m, 8);
      if (zo > zb || (zo == zb && to < bt)) { zb = zo; bt = to; }
    }
    const float A_ = __shfl(A,  bt, 8), B_ = __shfl(Bb, bt, 8);
    const float C_ = __shfl(C,  bt, 8), D_ = __shfl(D,  bt, 8);
    const float E_ = __shfl(E,  bt, 8), F_ = __shfl(F,  bt, 8);
    const float nx = A_ * px + B_ * py + E_;
    const float ny = C_ * px + D_ * py + F_;
    px = nx; py = ny;
  }

  if (lane == 0) {
    const float xc = ((px + 1.0f) * 0.5f) * (float)(kW - 1);
    const float yc = ((py + 1.0f) * 0.5f) * (float)(kH - 1);
    int xl = cvt_f32_i32_x86(floorf(xc));
    int yl = cvt_f32_i32_x86(floorf(yc));
    xl = min(max(xl, 0), kW - 2);
    yl = min(max(yl, 0), kH - 2);
    const float xw = xc - (float)xl;   // NOT clipped (matches reference)
    const float yw = yc - (float)yl;
    rec[n] = make_int4(xl, __float_as_int(xw), yl, __float_as_int(yw));
  }
}

// ---------------------------------------------------------------------------
// Kernel 2: persistent pipelined apply. 512 blocks x 1024 thr, 4 rows each.
// Per row: scatter(cur) -> issue loads(next) -> LDS-barrier ->
//          epilogue(read acc + bias + NT store + zero acc) -> LDS-barrier.
// Global loads/stores are never drained inside the loop.
// ---------------------------------------------------------------------------
__global__ __launch_bounds__(1024) void fractal_apply(
    const float* __restrict__ x, const float* __restrict__ bias,
    const int4* __restrict__ rec, float* __restrict__ out, int B) {
  __shared__ __align__(16) float acc[kH];        // 32 KB -> 2 blocks/CU
  const int tid = threadIdx.x;
  const int r0  = blockIdx.x * kRPB;

  // per-thread point record (threads 0..999)
  const bool hav = tid < kNP;
  int xl = 0, yl = 0;
  float xw = 0.f, yw = 0.f;
  if (hav) {
    const int4 rr = rec[tid];
    xl = rr.x; xw = __int_as_float(rr.y);
    yl = rr.z; yw = __int_as_float(rr.w);
  }
  const float xw0 = 1.0f - xw;
  const float w0  = 1.0f - yw;

  // initial zero of acc
  float4* acc4 = reinterpret_cast<float4*>(acc);
  acc4[tid]        = make_float4(0.f, 0.f, 0.f, 0.f);
  acc4[tid + 1024] = make_float4(0.f, 0.f, 0.f, 0.f);

  // prologue: issue row r0's gather loads
  float v0 = 0.f, v1 = 0.f;
  if (hav && r0 < B) {
    const float* xp = x + (size_t)r0 * kW + xl;
    v0 = xp[0];
    v1 = xp[1];
  }

  BAR_LDS();   // zeros visible to all; gather loads stay in flight

  const floatx4* __restrict__ bias4 = reinterpret_cast<const floatx4*>(bias);

  #pragma unroll
  for (int it = 0; it < kRPB; ++it) {
    const int r = r0 + it;
    if (r >= B) break;                        // block-uniform, barrier-safe

    // scatter current row (compiler inserts the precise vmcnt wait on v0/v1)
    if (hav) {
      const float xv = v0 * xw0 + v1 * xw;
      atomicAdd(&acc[yl],     xv * w0);
      atomicAdd(&acc[yl + 1], xv * yw);
    }

    // issue next row's loads NOW -- they fly across the barrier below
    if (hav && it + 1 < kRPB && r + 1 < B) {
      const float* xp = x + (size_t)(r + 1) * kW + xl;
      v0 = xp[0];
      v1 = xp[1];
    }

    BAR_LDS();   // all scatters done (lgkmcnt only; loads still in flight)

    // epilogue: out = acc/1000 + bias, then zero acc for the next row
    float* __restrict__ outrow = out + (size_t)r * kH;
    floatx4* __restrict__ out4 = reinterpret_cast<floatx4*>(outrow);
    #pragma unroll
    for (int j = 0; j < 2; ++j) {
      const int g = tid + j * 1024;
      const float4 a  = acc4[g];
      const floatx4 bi = bias4[g];
      floatx4 o;
      o.x = a.x / 1000.0f + bi.x;
      o.y = a.y / 1000.0f + bi.y;
      o.z = a.z / 1000.0f + bi.z;
      o.w = a.w / 1000.0f + bi.w;
      __builtin_nontemporal_store(o, &out4[g]);
      acc4[g] = make_float4(0.f, 0.f, 0.f, 0.f);   // fused re-zero
    }

    if (it + 1 < kRPB && r + 1 < B) {
      BAR_LDS(); // zeros + this row's acc reads done before next scatter
    }
  }
}

}  // namespace

extern "C" void kernel_launch(void* const* d_in, const int* in_sizes, int n_in,
                              void* d_out, int out_size, void* d_ws, size_t ws_size,
                              hipStream_t stream) {
  const float* x    = (const float*)d_in[0];   // (2048, 16384)
  const float* dna  = (const float*)d_in[1];   // (56,)
  const float* bias = (const float*)d_in[2];   // (8192,)
  float* out = (float*)d_out;                  // (2048, 8192)
  int4* rec = (int4*)d_ws;                     // 1000 * 16B scratch

  fractal_chaos<<<(kNP * 8 + 255) / 256, 256, 0, stream>>>(dna, rec);

  const int B = in_sizes[0] / kW;              // 2048
  fractal_apply<<<(B + kRPB - 1) / kRPB, 1024, 0, stream>>>(x, bias, rec,
                                                            out, B);
}